// Round 1
// baseline (42.210 us; speedup 1.0000x reference)
//
#include <hip/hip_runtime.h>

// AdaptiveHyperNN collapses algebraically: all layers are affine, so
// logit[b,u,v] = A[b,u] + B[b,v] + C[b] with
//   A = Feat @ va, B = Feat @ vb,
//   va = W2t@wa + W1b@(W2b@wa), vb = W2t@wb + W1b@(W2b@wb),
//   wa = W3[:D]@W4[:D,0],  wb = W3[D:]@W4[:D,0],
//   C[b] = fmean[b]·(W1t@(W2b@wa) + W1t@(W2b@wb)) + b1·(u2a+u2b)
//          + b2·(wa+wb) + b3·W4[:D] + Xs[b]·W4[D:] + b4.
// Total ~2.5 MFLOP — launch-latency bound.

__device__ __forceinline__ float wred(float v) {
#pragma unroll
  for (int o = 32; o > 0; o >>= 1) v += __shfl_xor(v, o, 64);
  return v;
}

// P1: gather feat + fmean (blocks 0..7), wa/wb = W3 row-dots with W4[:256]
// (blocks 8..15), c0[b] (block 16).
__global__ __launch_bounds__(256) void k_prep1(
    const float* __restrict__ Xs, const float* __restrict__ api,
    const float* __restrict__ W3, const float* __restrict__ b3,
    const float* __restrict__ W4, const float* __restrict__ b4,
    const int* __restrict__ invoked,
    float* __restrict__ feat, float* __restrict__ fmean,
    float* __restrict__ wa, float* __restrict__ wb, float* __restrict__ c0) {
  const int blk = blockIdx.x, tid = threadIdx.x;
  const int lane = tid & 63, wv = tid >> 6;
  if (blk < 8) {
    __shared__ int idx[128];
    if (tid < 128) idx[tid] = invoked[blk * 128 + tid];
    __syncthreads();
    float s = 0.f;
#pragma unroll 4
    for (int n = 0; n < 128; ++n) {
      float v = api[idx[n] * 256 + tid];
      feat[((blk * 128 + n) << 8) + tid] = v;
      s += v;
    }
    fmean[(blk << 8) + tid] = s * (1.f / 128.f);
  } else if (blk < 16) {
    float w40 = W4[lane], w41 = W4[lane + 64], w42 = W4[lane + 128], w43 = W4[lane + 192];
    int base = (blk - 8) * 64 + wv * 16;
    for (int i = 0; i < 16; ++i) {
      int r = base + i;  // 0..511 over W3 rows
      const float* row = W3 + r * 256;
      float s = row[lane] * w40 + row[lane + 64] * w41 +
                row[lane + 128] * w42 + row[lane + 192] * w43;
      s = wred(s);
      if (lane == 0) { if (r < 256) wa[r] = s; else wb[r - 256] = s; }
    }
  } else {
    float w40 = W4[lane], w41 = W4[lane + 64], w42 = W4[lane + 128], w43 = W4[lane + 192];
    float w80 = W4[256 + lane], w81 = W4[320 + lane], w82 = W4[384 + lane], w83 = W4[448 + lane];
    float sb3 = b3[lane] * w40 + b3[lane + 64] * w41 +
                b3[lane + 128] * w42 + b3[lane + 192] * w43;
    sb3 = wred(sb3);
    for (int bi = wv; bi < 8; bi += 4) {
      const float* xr = Xs + bi * 256;
      float xd = xr[lane] * w80 + xr[lane + 64] * w81 +
                 xr[lane + 128] * w82 + xr[lane + 192] * w83;
      xd = wred(xd);
      if (lane == 0) c0[bi] = b4[0] + sb3 + xd;
    }
  }
}

// P2: u2{a,b} = W2[256:]@{wa,wb}; w2t{a,b} = W2[:256]@{wa,wb}; sP2 = b2·(wa+wb)
__global__ __launch_bounds__(256) void k_prep2(
    const float* __restrict__ W2, const float* __restrict__ b2,
    const float* __restrict__ wa, const float* __restrict__ wb,
    float* __restrict__ u2a, float* __restrict__ u2b,
    float* __restrict__ w2ta, float* __restrict__ w2tb, float* __restrict__ sP2) {
  const int blk = blockIdx.x, tid = threadIdx.x;
  const int lane = tid & 63, wv = tid >> 6;
  float a0 = wa[lane], a1 = wa[lane + 64], a2 = wa[lane + 128], a3 = wa[lane + 192];
  float c0v = wb[lane], c1 = wb[lane + 64], c2 = wb[lane + 128], c3 = wb[lane + 192];
  if (blk < 16) {
    int base = blk * 32 + wv * 8;
    for (int i = 0; i < 8; ++i) {
      int r = base + i;  // 0..511 over W2 rows
      const float* row = W2 + r * 256;
      float r0 = row[lane], r1 = row[lane + 64], r2 = row[lane + 128], r3 = row[lane + 192];
      float sa = r0 * a0 + r1 * a1 + r2 * a2 + r3 * a3;
      float sb = r0 * c0v + r1 * c1 + r2 * c2 + r3 * c3;
      sa = wred(sa); sb = wred(sb);
      if (lane == 0) {
        if (r < 256) { w2ta[r] = sa; w2tb[r] = sb; }
        else         { u2a[r - 256] = sa; u2b[r - 256] = sb; }
      }
    }
  } else if (wv == 0) {
    float r0 = b2[lane], r1 = b2[lane + 64], r2 = b2[lane + 128], r3 = b2[lane + 192];
    float s = r0 * (a0 + c0v) + r1 * (a1 + c1) + r2 * (a2 + c2) + r3 * (a3 + c3);
    s = wred(s);
    if (lane == 0) *sP2 = s;
  }
}

// P3: qsum = W1[:256]@(u2a+u2b); va/vb = w2t{a,b} + W1[256:]@u2{a,b};
//     sAll = sP2 + b1·(u2a+u2b)
__global__ __launch_bounds__(256) void k_prep3(
    const float* __restrict__ W1, const float* __restrict__ b1,
    const float* __restrict__ u2a, const float* __restrict__ u2b,
    const float* __restrict__ w2ta, const float* __restrict__ w2tb,
    const float* __restrict__ sP2,
    float* __restrict__ va, float* __restrict__ vb,
    float* __restrict__ qsum, float* __restrict__ sAll) {
  const int blk = blockIdx.x, tid = threadIdx.x;
  const int lane = tid & 63, wv = tid >> 6;
  float a0 = u2a[lane], a1 = u2a[lane + 64], a2 = u2a[lane + 128], a3 = u2a[lane + 192];
  float b0 = u2b[lane], b1v = u2b[lane + 64], b2v = u2b[lane + 128], b3v = u2b[lane + 192];
  if (blk < 8) {
    int base = blk * 64 + wv * 16;
    for (int i = 0; i < 16; ++i) {
      int t = base + i;  // 0..511 over W1 rows (wave-uniform side of 256 split)
      const float* row = W1 + t * 256;
      float r0 = row[lane], r1 = row[lane + 64], r2 = row[lane + 128], r3 = row[lane + 192];
      if (t < 256) {
        float s = r0 * (a0 + b0) + r1 * (a1 + b1v) + r2 * (a2 + b2v) + r3 * (a3 + b3v);
        s = wred(s);
        if (lane == 0) qsum[t] = s;
      } else {
        float sa = r0 * a0 + r1 * a1 + r2 * a2 + r3 * a3;
        float sb = r0 * b0 + r1 * b1v + r2 * b2v + r3 * b3v;
        sa = wred(sa); sb = wred(sb);
        int k = t - 256;
        if (lane == 0) { va[k] = w2ta[k] + sa; vb[k] = w2tb[k] + sb; }
      }
    }
  } else if (wv == 0) {
    float s = b1[lane] * (a0 + b0) + b1[lane + 64] * (a1 + b1v) +
              b1[lane + 128] * (a2 + b2v) + b1[lane + 192] * (a3 + b3v);
    s = wred(s);
    if (lane == 0) *sAll = *sP2 + s;
  }
}

// K4: per graph b: A[u]=feat·va, B[v]=feat·vb, C = fmean·qsum + sAll + c0[b];
// out[b, u*128+v] = sigmoid(A[u]+B[v]+C)
__global__ __launch_bounds__(256) void k_final(
    const float* __restrict__ feat, const float* __restrict__ fmean,
    const float* __restrict__ va, const float* __restrict__ vb,
    const float* __restrict__ qsum, const float* __restrict__ sAll,
    const float* __restrict__ c0, float* __restrict__ out) {
  const int b = blockIdx.x, tid = threadIdx.x;
  const int lane = tid & 63, wv = tid >> 6;
  __shared__ float A[128], Bv[128], red[4], CbSh;
  float p = fmean[(b << 8) + tid] * qsum[tid];
  p = wred(p);
  if (lane == 0) red[wv] = p;
  __syncthreads();
  if (tid == 0) CbSh = red[0] + red[1] + red[2] + red[3] + sAll[0] + c0[b];
  float va0 = va[lane], va1 = va[lane + 64], va2 = va[lane + 128], va3 = va[lane + 192];
  float vb0 = vb[lane], vb1 = vb[lane + 64], vb2 = vb[lane + 128], vb3 = vb[lane + 192];
  for (int i = 0; i < 32; ++i) {
    int u = wv * 32 + i;
    const float* row = feat + (((b << 7) + u) << 8);
    float r0 = row[lane], r1 = row[lane + 64], r2 = row[lane + 128], r3 = row[lane + 192];
    float sa = r0 * va0 + r1 * va1 + r2 * va2 + r3 * va3;
    float sb = r0 * vb0 + r1 * vb1 + r2 * vb2 + r3 * vb3;
    sa = wred(sa); sb = wred(sb);
    if (lane == 0) { A[u] = sa; Bv[u] = sb; }
  }
  __syncthreads();
  float Cb = CbSh;
  float* ob = out + (b << 14);
#pragma unroll 8
  for (int e = tid; e < 16384; e += 256) {
    float x = A[e >> 7] + Bv[e & 127] + Cb;
    ob[e] = 1.f / (1.f + __expf(-x));
  }
}

extern "C" void kernel_launch(void* const* d_in, const int* in_sizes, int n_in,
                              void* d_out, int out_size, void* d_ws, size_t ws_size,
                              hipStream_t stream) {
  const float* Xs  = (const float*)d_in[0];
  const float* api = (const float*)d_in[1];
  const float* W1  = (const float*)d_in[2];
  const float* b1  = (const float*)d_in[3];
  const float* W2  = (const float*)d_in[4];
  const float* b2  = (const float*)d_in[5];
  const float* W3  = (const float*)d_in[6];
  const float* b3  = (const float*)d_in[7];
  const float* W4  = (const float*)d_in[8];
  const float* b4  = (const float*)d_in[9];
  const int* invoked = (const int*)d_in[10];
  float* out = (float*)d_out;

  float* ws   = (float*)d_ws;
  float* feat = ws;            // 262144 : [B*N, D]
  float* fmean= ws + 262144;   // 2048   : [B, D]
  float* wa   = ws + 264192;   // 256
  float* wb   = ws + 264448;   // 256
  float* c0   = ws + 264704;   // 8
  float* u2a  = ws + 264712;   // 256
  float* u2b  = ws + 264968;   // 256
  float* w2ta = ws + 265224;   // 256
  float* w2tb = ws + 265480;   // 256
  float* sP2  = ws + 265736;   // 1
  float* va   = ws + 265737;   // 256
  float* vb   = ws + 265993;   // 256
  float* qsum = ws + 266249;   // 256
  float* sAll = ws + 266505;   // 1     (total ~1.07 MB)

  hipLaunchKernelGGL(k_prep1, dim3(17), dim3(256), 0, stream,
                     Xs, api, W3, b3, W4, b4, invoked, feat, fmean, wa, wb, c0);
  hipLaunchKernelGGL(k_prep2, dim3(17), dim3(256), 0, stream,
                     W2, b2, wa, wb, u2a, u2b, w2ta, w2tb, sP2);
  hipLaunchKernelGGL(k_prep3, dim3(9), dim3(256), 0, stream,
                     W1, b1, u2a, u2b, w2ta, w2tb, sP2, va, vb, qsum, sAll);
  hipLaunchKernelGGL(k_final, dim3(8), dim3(256), 0, stream,
                     feat, fmean, va, vb, qsum, sAll, c0, out);
}

// Round 2
// 25.138 us; speedup vs baseline: 1.6791x; 1.6791x over previous
//
#include <hip/hip_runtime.h>

// AdaptiveHyperNN collapses algebraically (all layers affine until sigmoid):
//   logit[b,u,v] = A[b,u] + B[b,v] + C[b]
//   A = Feat@va, B = Feat@vb
//   wa = W3[:D]@w4t, wb = W3[D:]@w4t           (w4t = W4[:D,0])
//   u2{a,b} = W2[D:]@w{a,b}, w2t{a,b} = W2[:D]@w{a,b}
//   va/vb = w2t{a,b} + W1[D:]@u2{a,b}, qsum = W1[:D]@(u2a+u2b)
//   C[b] = (1/128)*sum_u feat[b,u]·qsum + b1·(u2a+u2b) + b2·(wa+wb)
//          + b3·w4t + Xs[b]·W4[D:,0] + b4
// ~2.5 MFLOP total. Previous version was latency-bound (tiny grids, deep
// per-thread loops). This version: every stage is depth-1, one wave per row.

__device__ __forceinline__ float wred(float v) {
#pragma unroll
  for (int o = 32; o > 0; o >>= 1) v += __shfl_xor(v, o, 64);
  return v;
}
__device__ __forceinline__ float dot4(float4 a, float4 b) {
  return a.x * b.x + a.y * b.y + a.z * b.z + a.w * b.w;
}

// L1: blocks 0..255 gather feat (wave per row, one float4/lane);
//     blocks 256..383: wa/wb = W3 row-dots with w4t (wave per row);
//     block 384: c0[b] = b3·w4t + Xs[b]·w4b + b4.
__global__ __launch_bounds__(256) void k_prep1(
    const float* __restrict__ Xs, const float* __restrict__ api,
    const float* __restrict__ W3, const float* __restrict__ b3,
    const float* __restrict__ W4, const float* __restrict__ b4,
    const int* __restrict__ invoked,
    float* __restrict__ feat, float* __restrict__ wa, float* __restrict__ wb,
    float* __restrict__ c0) {
  const int blk = blockIdx.x, tid = threadIdx.x;
  const int lane = tid & 63, wv = tid >> 6;
  if (blk < 256) {
    int row = blk * 4 + wv;  // 0..1023  (= b*128 + n)
    int idx = invoked[row];  // wave-uniform -> scalar load
    ((float4*)(feat + row * 256))[lane] =
        ((const float4*)(api + idx * 256))[lane];
  } else if (blk < 384) {
    int r = (blk - 256) * 4 + wv;  // 0..511 over W3 rows
    float4 w4 = ((const float4*)W4)[lane];
    float4 rv = ((const float4*)(W3 + r * 256))[lane];
    float s = wred(dot4(rv, w4));
    if (lane == 0) { if (r < 256) wa[r] = s; else wb[r - 256] = s; }
  } else {
    float4 w4a = ((const float4*)W4)[lane];
    float4 w4b = ((const float4*)W4)[lane + 64];
    float sb3 = wred(dot4(((const float4*)b3)[lane], w4a));
    for (int bi = wv; bi < 8; bi += 4) {
      float xd = wred(dot4(((const float4*)(Xs + bi * 256))[lane], w4b));
      if (lane == 0) c0[bi] = b4[0] + sb3 + xd;
    }
  }
}

// L2: blocks 0..127 wave-per-row over W2 (512 rows): dots with wa, wb;
//     block 128: sP2 = b2·(wa+wb).
__global__ __launch_bounds__(256) void k_prep2(
    const float* __restrict__ W2, const float* __restrict__ b2,
    const float* __restrict__ wa, const float* __restrict__ wb,
    float* __restrict__ u2a, float* __restrict__ u2b,
    float* __restrict__ w2ta, float* __restrict__ w2tb,
    float* __restrict__ sP2) {
  const int blk = blockIdx.x, tid = threadIdx.x;
  const int lane = tid & 63, wv = tid >> 6;
  float4 a4 = ((const float4*)wa)[lane];
  float4 b4v = ((const float4*)wb)[lane];
  if (blk < 128) {
    int r = blk * 4 + wv;  // 0..511
    float4 rv = ((const float4*)(W2 + r * 256))[lane];
    float sa = wred(dot4(rv, a4));
    float sb = wred(dot4(rv, b4v));
    if (lane == 0) {
      if (r < 256) { w2ta[r] = sa; w2tb[r] = sb; }
      else         { u2a[r - 256] = sa; u2b[r - 256] = sb; }
    }
  } else if (wv == 0) {
    float4 bb = ((const float4*)b2)[lane];
    float4 s4 = make_float4(a4.x + b4v.x, a4.y + b4v.y,
                            a4.z + b4v.z, a4.w + b4v.w);
    float s = wred(dot4(bb, s4));
    if (lane == 0) *sP2 = s;
  }
}

// L3: blocks 0..127 wave-per-row over W1 (512 rows):
//     t<256 -> qsum[t] = row·(u2a+u2b); t>=256 -> va/vb = w2t + row·u2{a,b};
//     block 128: sAll = sP2 + b1·(u2a+u2b).
__global__ __launch_bounds__(256) void k_prep3(
    const float* __restrict__ W1, const float* __restrict__ b1,
    const float* __restrict__ u2a, const float* __restrict__ u2b,
    const float* __restrict__ w2ta, const float* __restrict__ w2tb,
    const float* __restrict__ sP2,
    float* __restrict__ va, float* __restrict__ vb,
    float* __restrict__ qsum, float* __restrict__ sAll) {
  const int blk = blockIdx.x, tid = threadIdx.x;
  const int lane = tid & 63, wv = tid >> 6;
  float4 a4 = ((const float4*)u2a)[lane];
  float4 b4v = ((const float4*)u2b)[lane];
  if (blk < 128) {
    int t = blk * 4 + wv;  // 0..511
    float4 rv = ((const float4*)(W1 + t * 256))[lane];
    if (t < 256) {
      float s = wred(dot4(rv, a4) + dot4(rv, b4v));
      if (lane == 0) qsum[t] = s;
    } else {
      float sa = wred(dot4(rv, a4));
      float sb = wred(dot4(rv, b4v));
      int k = t - 256;
      if (lane == 0) { va[k] = w2ta[k] + sa; vb[k] = w2tb[k] + sb; }
    }
  } else if (wv == 0) {
    float4 bb = ((const float4*)b1)[lane];
    float s = wred(dot4(bb, a4) + dot4(bb, b4v));
    if (lane == 0) *sAll = *sP2 + s;
  }
}

// L4: one block (1024 thr = 16 waves) per graph. 8 rows/wave: dots with
// va, vb, qsum (qsum dot folds the old fmean·qsum term). Then float4
// sigmoid stores of A[u]+B[v]+C.
__global__ __launch_bounds__(1024) void k_final(
    const float* __restrict__ feat,
    const float* __restrict__ va, const float* __restrict__ vb,
    const float* __restrict__ qsum, const float* __restrict__ sAll,
    const float* __restrict__ c0, float* __restrict__ out) {
  const int b = blockIdx.x, tid = threadIdx.x;
  const int lane = tid & 63, wv = tid >> 6;  // wv 0..15
  __shared__ float A[128], Bv[128], red[16], CbSh;
  float4 va4 = ((const float4*)va)[lane];
  float4 vb4 = ((const float4*)vb)[lane];
  float4 q4  = ((const float4*)qsum)[lane];
  float scacc = 0.f;
#pragma unroll
  for (int i = 0; i < 8; ++i) {
    int u = wv * 8 + i;
    float4 rv = ((const float4*)(feat + ((b << 7) + u) * 256))[lane];
    float sa = wred(dot4(rv, va4));
    float sb = wred(dot4(rv, vb4));
    float sc = wred(dot4(rv, q4));
    if (lane == 0) { A[u] = sa; Bv[u] = sb; }
    scacc += sc;
  }
  if (lane == 0) red[wv] = scacc;
  __syncthreads();
  if (tid == 0) {
    float s = 0.f;
#pragma unroll
    for (int i = 0; i < 16; ++i) s += red[i];
    CbSh = s * (1.f / 128.f) + sAll[0] + c0[b];
  }
  __syncthreads();
  float Cb = CbSh;
  float4* ob = (float4*)(out + (b << 14));
#pragma unroll
  for (int it = 0; it < 4; ++it) {
    int e4 = it * 1024 + tid;  // float4 index within graph
    int e = e4 * 4;
    float a = A[e >> 7];
    int v0 = e & 127;
    float4 r;
    r.x = 1.f / (1.f + __expf(-(a + Bv[v0 + 0] + Cb)));
    r.y = 1.f / (1.f + __expf(-(a + Bv[v0 + 1] + Cb)));
    r.z = 1.f / (1.f + __expf(-(a + Bv[v0 + 2] + Cb)));
    r.w = 1.f / (1.f + __expf(-(a + Bv[v0 + 3] + Cb)));
    ob[e4] = r;
  }
}

extern "C" void kernel_launch(void* const* d_in, const int* in_sizes, int n_in,
                              void* d_out, int out_size, void* d_ws, size_t ws_size,
                              hipStream_t stream) {
  const float* Xs  = (const float*)d_in[0];
  const float* api = (const float*)d_in[1];
  const float* W1  = (const float*)d_in[2];
  const float* b1  = (const float*)d_in[3];
  const float* W2  = (const float*)d_in[4];
  const float* b2  = (const float*)d_in[5];
  const float* W3  = (const float*)d_in[6];
  const float* b3  = (const float*)d_in[7];
  const float* W4  = (const float*)d_in[8];
  const float* b4  = (const float*)d_in[9];
  const int* invoked = (const int*)d_in[10];
  float* out = (float*)d_out;

  float* ws   = (float*)d_ws;
  float* feat = ws;            // 262144 : [B*N, D]
  float* wa   = ws + 262144;   // 256
  float* wb   = ws + 262400;   // 256
  float* c0   = ws + 262656;   // 8
  float* u2a  = ws + 262664;   // 256
  float* u2b  = ws + 262920;   // 256
  float* w2ta = ws + 263176;   // 256
  float* w2tb = ws + 263432;   // 256
  float* sP2  = ws + 263688;   // 1
  float* va   = ws + 263689;   // 256
  float* vb   = ws + 263945;   // 256
  float* qsum = ws + 264201;   // 256
  float* sAll = ws + 264457;   // 1

  hipLaunchKernelGGL(k_prep1, dim3(385), dim3(256), 0, stream,
                     Xs, api, W3, b3, W4, b4, invoked, feat, wa, wb, c0);
  hipLaunchKernelGGL(k_prep2, dim3(129), dim3(256), 0, stream,
                     W2, b2, wa, wb, u2a, u2b, w2ta, w2tb, sP2);
  hipLaunchKernelGGL(k_prep3, dim3(129), dim3(256), 0, stream,
                     W1, b1, u2a, u2b, w2ta, w2tb, sP2, va, vb, qsum, sAll);
  hipLaunchKernelGGL(k_final, dim3(8), dim3(1024), 0, stream,
                     feat, va, vb, qsum, sAll, c0, out);
}